// Round 3
// baseline (73.350 us; speedup 1.0000x reference)
//
#include <hip/hip_runtime.h>
#include <math.h>

#define W       704
#define K       11
#define NBX     64            // 704 / 11 blocks per strip row
#define NBLK    1024          // workgroups; each handles 2 strips (22 rows)
#define NF4     176           // 704 / 4 float4 per row
#define PAD_W   708           // scol leading dim: 16B-aligned float4 stores, 2-way-max banks
#define NTOT    131072.0f     // 32 * 64 * 64 output blocks
#define C_CONST 0.0009f

__device__ __forceinline__ void accum_strip(
    const float4* __restrict__ vp, const float4* __restrict__ ip,
    const float4* __restrict__ fp, float acc[8][4])
{
    #pragma unroll
    for (int q = 0; q < 8; ++q)
        #pragma unroll
        for (int c = 0; c < 4; ++c) acc[q][c] = 0.f;
    #pragma unroll
    for (int r = 0; r < K; ++r) {
        float4 v4 = vp[r * NF4];
        float4 i4 = ip[r * NF4];
        float4 f4 = fp[r * NF4];
        float vv[4] = {v4.x, v4.y, v4.z, v4.w};
        float ii[4] = {i4.x, i4.y, i4.z, i4.w};
        float ff[4] = {f4.x, f4.y, f4.z, f4.w};
        #pragma unroll
        for (int c = 0; c < 4; ++c) {
            float v = vv[c], i = ii[c], f = ff[c];
            acc[0][c] += v;     acc[1][c] += i;     acc[2][c] += f;
            acc[3][c] += v * v; acc[4][c] += i * i; acc[5][c] += f * f;
            acc[6][c] += v * f; acc[7][c] += i * f;
        }
    }
}

__device__ __forceinline__ float block_score(const float* __restrict__ s)
{
    const float invn = 1.0f / 121.0f;
    float mv = s[0] * invn, mi = s[1] * invn, mf = s[2] * invn;
    float var_v = fabsf(s[3] * invn - mv * mv);
    float var_i = fabsf(s[4] * invn - mi * mi);
    float var_f = fabsf(s[5] * invn - mf * mf);
    float cov_vf = s[6] * invn - mv * mf;
    float cov_if = s[7] * invn - mi * mf;
    float l_vf = (2.f * mv * mf + C_CONST) / (mv * mv + mf * mf + C_CONST);
    float l_if = (2.f * mi * mf + C_CONST) / (mi * mi + mf * mf + C_CONST);
    float s_vf = (cov_vf + C_CONST) / (var_v + var_f + C_CONST);
    float s_if = (cov_if + C_CONST) / (var_i + var_f + C_CONST);
    return (mv > mi) ? (l_vf * s_vf) : (l_if * s_if);
}

__global__ __launch_bounds__(256, 4) void vif_fused_kernel(
    const float* __restrict__ vis,
    const float* __restrict__ inf,
    const float* __restrict__ fus,
    float* __restrict__ partials,        // NBLK floats in d_ws
    unsigned int* __restrict__ counter,  // zeroed each launch
    float* __restrict__ out)
{
    __shared__ float scol[8][PAD_W];     // per-column sums, one strip at a time
    __shared__ float sred[NBX][9];       // per-11x11-block sums (pad 9: bank-clean)
    __shared__ unsigned int lastRank;
    __shared__ float red[4];

    const int t = threadIdx.x;
    const size_t base0 = (size_t)(2 * blockIdx.x) * (K * W);   // 22 contiguous rows
    const bool loader = (t < NF4);

    float acc0[8][4], acc1[8][4];
    float scoreSum = 0.f;

    // ---- phase 1: issue ALL loads (both strips), stage strip 0 ----
    if (loader) {
        const float4* vp = (const float4*)(vis + base0) + t;
        const float4* ip = (const float4*)(inf + base0) + t;
        const float4* fp = (const float4*)(fus + base0) + t;
        accum_strip(vp, ip, fp, acc0);
        accum_strip(vp + K * NF4, ip + K * NF4, fp + K * NF4, acc1);
        #pragma unroll
        for (int q = 0; q < 8; ++q)
            *(float4*)&scol[q][4 * t] =
                make_float4(acc0[q][0], acc0[q][1], acc0[q][2], acc0[q][3]);
    }
    __syncthreads();

    // ---- phase 2: reduce strip-0 columns -> block sums ----
    for (int task = t; task < NBX * 8; task += 256) {
        int bx = task >> 3, q = task & 7;
        float s = 0.f;
        #pragma unroll
        for (int j = 0; j < K; ++j) s += scol[q][bx * K + j];
        sred[bx][q] = s;
    }
    __syncthreads();

    // ---- phase 3: score strip 0 (wave 0) || stage strip 1 (loaders) ----
    if (t < NBX) scoreSum += block_score(sred[t]);
    if (loader) {
        #pragma unroll
        for (int q = 0; q < 8; ++q)
            *(float4*)&scol[q][4 * t] =
                make_float4(acc1[q][0], acc1[q][1], acc1[q][2], acc1[q][3]);
    }
    __syncthreads();

    // ---- phase 4: reduce strip-1 columns ----
    for (int task = t; task < NBX * 8; task += 256) {
        int bx = task >> 3, q = task & 7;
        float s = 0.f;
        #pragma unroll
        for (int j = 0; j < K; ++j) s += scol[q][bx * K + j];
        sred[bx][q] = s;
    }
    __syncthreads();

    // ---- phase 5: score strip 1, wave-0 shuffle reduce, ticket ----
    if (t < NBX) scoreSum += block_score(sred[t]);

    if (t < 64) {   // exactly wave 0 — deterministic
        #pragma unroll
        for (int off = 32; off > 0; off >>= 1)
            scoreSum += __shfl_down(scoreSum, off);
        if (t == 0) {
            partials[blockIdx.x] = scoreSum;
            __threadfence();                       // publish before ticket
            lastRank = atomicAdd(counter, 1u);     // device-scope
        }
    }
    __syncthreads();

    if (lastRank == NBLK - 1) {
        // winner block: all other partials are published. Agent-scope atomic
        // loads bypass any stale per-XCD L2 copy left by the previous replay.
        __threadfence();
        float s = 0.f;
        #pragma unroll
        for (int k = 0; k < 4; ++k)
            s += __hip_atomic_load(&partials[t + 256 * k],
                                   __ATOMIC_RELAXED, __HIP_MEMORY_SCOPE_AGENT);
        #pragma unroll
        for (int off = 32; off > 0; off >>= 1)
            s += __shfl_down(s, off);
        if ((t & 63) == 0) red[t >> 6] = s;
        __syncthreads();
        if (t == 0) {
            float tot = red[0] + red[1] + red[2] + red[3];
            out[0] = 1.0f - tot / NTOT;
        }
    }
}

extern "C" void kernel_launch(void* const* d_in, const int* in_sizes, int n_in,
                              void* d_out, int out_size, void* d_ws, size_t ws_size,
                              hipStream_t stream)
{
    const float* vis = (const float*)d_in[0];
    const float* inf = (const float*)d_in[1];
    const float* fus = (const float*)d_in[2];
    float* out = (float*)d_out;
    float* partials = (float*)d_ws;                          // 1024 floats
    unsigned int* counter = (unsigned int*)((char*)d_ws + NBLK * sizeof(float));

    hipMemsetAsync(counter, 0, sizeof(unsigned int), stream);
    vif_fused_kernel<<<NBLK, 256, 0, stream>>>(vis, inf, fus, partials, counter, out);
}